// Round 1
// baseline (154.535 us; speedup 1.0000x reference)
//
#include <hip/hip_runtime.h>

#define DEG 32
#define HID 32
#define CIN 8

// gelu(x) = 0.5x(1+tanh(sqrt(2/pi)(x + 0.044715 x^3)))   [jax approximate=True]
//         = x * (1 - rcp(1 + exp2( x*(A + B*x^2) )))
// A = 2*log2(e)*sqrt(2/pi), B = A*0.044715
__device__ __forceinline__ float gelu_tanh(float x) {
    constexpr float A = (float)(2.0 * 1.4426950408889634 * 0.7978845608028654);
    constexpr float B = (float)(2.0 * 1.4426950408889634 * 0.7978845608028654 * 0.044715);
    float x2 = x * x;
    float z  = x * fmaf(B, x2, A);
    float e  = __builtin_amdgcn_exp2f(z);
    float r  = __builtin_amdgcn_rcpf(1.0f + e);
    return x - x * r;   // x -> -inf: r->1, result 0.  x -> +inf: r->0, result x.
}

// Phase 1: per-node u = x @ W1[:8], v = x @ W1[8:] + b1
__global__ __launch_bounds__(256) void precompute_uv(
    const float* __restrict__ x, const float* __restrict__ W1,
    const float* __restrict__ b1, float* __restrict__ u, float* __restrict__ v,
    int N) {
    int tid = blockIdx.x * 256 + threadIdx.x;
    if (tid >= N * HID) return;
    int n = tid >> 5;
    int h = tid & 31;
    const float4* xp = (const float4*)(x + (size_t)n * CIN);
    float4 a = xp[0], b = xp[1];
    float xv[8] = {a.x, a.y, a.z, a.w, b.x, b.y, b.z, b.w};
    float su = 0.f, sv = b1[h];
#pragma unroll
    for (int k = 0; k < 8; ++k) {
        su = fmaf(xv[k], W1[k * HID + h], su);
        sv = fmaf(xv[k], W1[(k + 8) * HID + h], sv);
    }
    u[tid] = su;
    v[tid] = sv;
}

// Phase 2: one wave per node. lane = half*32 + hid. Each half-wave handles one
// edge per iteration (2 edges/wave/iter, 16 iters). g[hid] = sum_j w_j*gelu(u_j+v_i),
// then per-node out = (g @ W2 + ws*b2) / 32.
__global__ __launch_bounds__(256) void main_pre(
    const float* __restrict__ u, const float* __restrict__ v,
    const float* __restrict__ wgt, const float* __restrict__ W2,
    const float* __restrict__ b2, const int* __restrict__ nbr,
    float* __restrict__ out, int N) {
    __shared__ float sW2[HID * HID];
    __shared__ float sb2[HID];
    int t = threadIdx.x;
#pragma unroll
    for (int i = 0; i < 4; ++i) sW2[t + i * 256] = W2[t + i * 256];
    if (t < HID) sb2[t] = b2[t];
    __syncthreads();

    int wave = t >> 6;
    int lane = t & 63;
    int half = lane >> 5;
    int hid  = lane & 31;
    int node = blockIdx.x * 4 + wave;
    if (node >= N) return;

    // preload this node's 32 neighbor ids + their weights into lanes (dup in halves)
    int   j_l = nbr[node * DEG + (lane & 31)];
    float w_l = wgt[j_l];
    float vb  = v[(size_t)node * HID + hid];

    float g = 0.f, ws = 0.f;
#pragma unroll
    for (int it = 0; it < 16; ++it) {
        int   src = it * 2 + half;
        int   j   = __shfl(j_l, src);
        float wj  = __shfl(w_l, src);
        float uj  = u[(size_t)j * HID + hid];     // 128B coalesced per half-wave
        float hg  = gelu_tanh(uj + vb);
        g  = fmaf(wj, hg, g);
        ws += wj;
    }
    g  += __shfl_xor(g, 32);
    ws += __shfl_xor(ws, 32);

    // second matmul: lane -> output channel hid; halves split the h-range
    float acc = 0.f;
#pragma unroll
    for (int hh = 0; hh < 16; ++hh) {
        int h = half * 16 + hh;
        float gh = __shfl(g, h);
        acc = fmaf(gh, sW2[h * HID + hid], acc);
    }
    acc += __shfl_xor(acc, 32);
    if (half == 0) {
        out[(size_t)node * HID + hid] = (acc + ws * sb2[hid]) * (1.0f / 32.0f);
    }
}

// Fallback (no workspace): recompute u_j on the fly from x_j (L2-resident 3.2MB table)
__global__ __launch_bounds__(256) void main_fly(
    const float* __restrict__ x, const float* __restrict__ wgt,
    const float* __restrict__ W1, const float* __restrict__ b1,
    const float* __restrict__ W2, const float* __restrict__ b2,
    const int* __restrict__ nbr, float* __restrict__ out, int N) {
    __shared__ float sW2[HID * HID];
    __shared__ float sb2[HID];
    int t = threadIdx.x;
#pragma unroll
    for (int i = 0; i < 4; ++i) sW2[t + i * 256] = W2[t + i * 256];
    if (t < HID) sb2[t] = b2[t];
    __syncthreads();

    int wave = t >> 6;
    int lane = t & 63;
    int half = lane >> 5;
    int hid  = lane & 31;
    int node = blockIdx.x * 4 + wave;
    if (node >= N) return;

    float w1t[8], w1b[8];
#pragma unroll
    for (int k = 0; k < 8; ++k) {
        w1t[k] = W1[k * HID + hid];
        w1b[k] = W1[(k + 8) * HID + hid];
    }
    const float4* xip = (const float4*)(x + (size_t)node * CIN);
    float4 xa = xip[0], xb = xip[1];
    float vb = b1[hid];
    vb = fmaf(xa.x, w1b[0], vb); vb = fmaf(xa.y, w1b[1], vb);
    vb = fmaf(xa.z, w1b[2], vb); vb = fmaf(xa.w, w1b[3], vb);
    vb = fmaf(xb.x, w1b[4], vb); vb = fmaf(xb.y, w1b[5], vb);
    vb = fmaf(xb.z, w1b[6], vb); vb = fmaf(xb.w, w1b[7], vb);

    int   j_l = nbr[node * DEG + (lane & 31)];
    float w_l = wgt[j_l];

    float g = 0.f, ws = 0.f;
#pragma unroll
    for (int it = 0; it < 16; ++it) {
        int   src = it * 2 + half;
        int   j   = __shfl(j_l, src);
        float wj  = __shfl(w_l, src);
        const float4* xjp = (const float4*)(x + (size_t)j * CIN);
        float4 a = xjp[0], b = xjp[1];
        float tin = vb;
        tin = fmaf(a.x, w1t[0], tin); tin = fmaf(a.y, w1t[1], tin);
        tin = fmaf(a.z, w1t[2], tin); tin = fmaf(a.w, w1t[3], tin);
        tin = fmaf(b.x, w1t[4], tin); tin = fmaf(b.y, w1t[5], tin);
        tin = fmaf(b.z, w1t[6], tin); tin = fmaf(b.w, w1t[7], tin);
        float hg = gelu_tanh(tin);
        g  = fmaf(wj, hg, g);
        ws += wj;
    }
    g  += __shfl_xor(g, 32);
    ws += __shfl_xor(ws, 32);

    float acc = 0.f;
#pragma unroll
    for (int hh = 0; hh < 16; ++hh) {
        int h = half * 16 + hh;
        float gh = __shfl(g, h);
        acc = fmaf(gh, sW2[h * HID + hid], acc);
    }
    acc += __shfl_xor(acc, 32);
    if (half == 0) {
        out[(size_t)node * HID + hid] = (acc + ws * sb2[hid]) * (1.0f / 32.0f);
    }
}

extern "C" void kernel_launch(void* const* d_in, const int* in_sizes, int n_in,
                              void* d_out, int out_size, void* d_ws, size_t ws_size,
                              hipStream_t stream) {
    const float* x   = (const float*)d_in[0];
    const float* wq  = (const float*)d_in[1];
    const float* W1  = (const float*)d_in[2];
    const float* b1  = (const float*)d_in[3];
    const float* W2  = (const float*)d_in[4];
    const float* b2  = (const float*)d_in[5];
    const int*   nbr = (const int*)d_in[6];
    float* out = (float*)d_out;

    int N = in_sizes[1];            // in_weights has N elements
    size_t need = (size_t)N * HID * 2 * sizeof(float);
    int blocks_main = (N + 3) / 4;  // 4 nodes (waves) per 256-thread block

    if (ws_size >= need) {
        float* u = (float*)d_ws;
        float* v = u + (size_t)N * HID;
        int blocks_pre = (N * HID + 255) / 256;
        precompute_uv<<<blocks_pre, 256, 0, stream>>>(x, W1, b1, u, v, N);
        main_pre<<<blocks_main, 256, 0, stream>>>(u, v, wq, W2, b2, nbr, out, N);
    } else {
        main_fly<<<blocks_main, 256, 0, stream>>>(x, wq, W1, b1, W2, b2, nbr, out, N);
    }
}